// Round 21
// baseline (154.407 us; speedup 1.0000x reference)
//
#include <hip/hip_runtime.h>
#include <cstdint>
#include <cstddef>

// Problem constants
#define B_ 8
#define C_ 512
#define L_ 4096
#define M_ 2048   // L/2 (pooled keys)
#define CK_ 64    // C/8
#define CV_ 256   // C/2

typedef _Float16 f16;
typedef _Float16 f16x8 __attribute__((ext_vector_type(8)));
typedef _Float16 f16x4 __attribute__((ext_vector_type(4)));
typedef float f32x4 __attribute__((ext_vector_type(4)));
typedef float f32x16 __attribute__((ext_vector_type(16)));
typedef unsigned int u32x4 __attribute__((ext_vector_type(4)));

#define MFMA16(A, Bv, Cv) __builtin_amdgcn_mfma_f32_16x16x32_f16(A, Bv, Cv, 0, 0, 0)
#define MFMA32(A, Bv, Cv) __builtin_amdgcn_mfma_f32_32x32x16_f16(A, Bv, Cv, 0, 0, 0)

#define LOG2E 1.44269504f

static __device__ __forceinline__ uint32_t pkrtz(float a, float b) {
    return __builtin_bit_cast(uint32_t, __builtin_amdgcn_cvt_pkrtz(a, b));
}

// ---------------------------------------------------------------------------
// Kernel W: weight conversion into FRAGMENT-NATIVE layouts. (r11-verified)
// ---------------------------------------------------------------------------
__global__ __launch_bounds__(256) void cvt_all(const float* __restrict__ Wt,
                                               const float* __restrict__ Wp,
                                               const float* __restrict__ Wg,
                                               const float* __restrict__ Wo,
                                               f16* __restrict__ WallF,
                                               f16* __restrict__ WoF) {
    const int i = blockIdx.x * 256 + threadIdx.x;
    const int NW = 384 * 512;  // 196608
    if (i < NW) {
        const int och = i >> 9, c = i & 511;
        float v;
        if (och < 64)       v = Wt[i];
        else if (och < 128) v = Wp[i - 64 * 512];
        else                v = Wg[i - 128 * 512];
        const int idx = (((och >> 4) * 16 + (c >> 5)) * 64 +
                         (((c >> 3) & 3) << 4) + (och & 15)) * 8 + (c & 7);
        WallF[idx] = (f16)v;
    } else {
        const int j = i - NW;  // < 131072
        const int oc = j >> 8, v = j & 255;
        const int idx = (((oc >> 4) * 8 + (v >> 5)) * 64 +
                         (((v >> 3) & 3) << 4) + (oc & 15)) * 8 + (v & 7);
        WoF[idx] = (f16)Wo[j];
    }
}

// ---------------------------------------------------------------------------
// Fused projection kernel (MFMA f16, fp32 accum), x staged via LDS.
//   (r11-verified, unchanged)
// ---------------------------------------------------------------------------
__global__ __launch_bounds__(256) void fused_proj(const f16* __restrict__ WallF,
                                                  const float* __restrict__ x,
                                                  f16* __restrict__ theta2,
                                                  f16* __restrict__ phi2,
                                                  f16* __restrict__ g2) {
    __shared__ __align__(16) f16 xs[64][32][8];  // 32 KB
    const int b    = blockIdx.y;
    const int l0   = blockIdx.x * 32;
    const int tid  = threadIdx.x;
    const int w    = tid >> 6;           // warp: och range [w*96, w*96+96)
    const int lane = tid & 63;
    const int lq   = lane & 15;
    const int g    = lane >> 4;
    const int wb   = w * 96;

    // ---- stage x tile -> LDS (f16, fragment-native) ----
    {
        const float* xb = x + (size_t)b * C_ * L_ + l0 + (tid & 31);
        const int co0 = tid >> 5;  // 0..7
#pragma unroll
        for (int i = 0; i < 8; ++i) {
            const int co = i * 8 + co0;
            float v[8];
#pragma unroll
            for (int j = 0; j < 8; ++j) v[j] = xb[(size_t)(co * 8 + j) * L_];
            u32x4 p = {pkrtz(v[0], v[1]), pkrtz(v[2], v[3]),
                       pkrtz(v[4], v[5]), pkrtz(v[6], v[7])};
            *reinterpret_cast<u32x4*>(&xs[co][tid & 31][0]) = p;
        }
    }
    __syncthreads();

    f32x4 acc[6][2] = {};
    for (int ks = 0; ks < 16; ++ks) {
        f16x8 Bf[2];
#pragma unroll
        for (int lt = 0; lt < 2; ++lt)
            Bf[lt] = *reinterpret_cast<const f16x8*>(&xs[ks * 4 + g][lt * 16 + lq][0]);
#pragma unroll
        for (int t = 0; t < 6; ++t) {
            f16x8 Af = *reinterpret_cast<const f16x8*>(
                WallF + (((size_t)(6 * w + t) * 16 + ks) * 64 + lane) * 8);
            acc[t][0] = MFMA16(Af, Bf[0], acc[t][0]);
            acc[t][1] = MFMA16(Af, Bf[1], acc[t][1]);
        }
    }

    // Epilogue. D layout (MFMA16): row = 4g + r (och), col = lq (l).
#pragma unroll
    for (int t = 0; t < 6; ++t) {
        const int och0 = wb + t * 16;
#pragma unroll
        for (int lt = 0; lt < 2; ++lt) {
            const int l = l0 + lt * 16 + lq;
            if (och0 < 64) {
#pragma unroll
                for (int r = 0; r < 4; ++r) {
                    const int och = och0 + 4 * g + r;
                    theta2[(((size_t)b * 8 + (och >> 3)) * L_ + l) * 8 + (och & 7)] =
                        (f16)(acc[t][lt][r] * LOG2E);
                }
            } else {
#pragma unroll
                for (int r = 0; r < 4; ++r) {
                    const float pv = fmaxf(acc[t][lt][r], __shfl_xor(acc[t][lt][r], 1));
                    if (!(lane & 1)) {
                        const int m = l >> 1;
                        if (och0 < 128) {
                            const int kc = och0 - 64 + 4 * g + r;
                            phi2[(((size_t)b * 8 + (kc >> 3)) * M_ + m) * 8 + (kc & 7)] =
                                (f16)pv;
                        } else {
                            const int vc = och0 - 128 + 4 * g + r;
                            g2[(((size_t)b * 256 + (m >> 3)) * CV_ + vc) * 8 + (m & 7)] =
                                (f16)pv;
                        }
                    }
                }
            }
        }
    }
}

// ---------------------------------------------------------------------------
// Kernel B: flash attention, split-M across blocks (grid.y = mh), vq = 2.
//   EXACT r15-verified body (best measured: 79.3 µs; register-equilibrium
//   accepted per r16 — NMH=4 and occupancy probes were null).
// ---------------------------------------------------------------------------
__global__ __launch_bounds__(256, 3) void attn_flash(const f16* __restrict__ theta2,
                                                     const f16* __restrict__ phi2,
                                                     const f16* __restrict__ g2,
                                                     f16* __restrict__ op,
                                                     float* __restrict__ mlm,
                                                     float* __restrict__ mll) {
    const int bid = blockIdx.x;
    const int mh  = blockIdx.y;         // m-stripe of 1024
    const int b   = bid & 7;            // XCD-major: one batch per XCD
    const int qt  = bid >> 3;           // 64 q-tiles (of 64) per batch
    const int w   = threadIdx.x >> 6;   // 0..3
    const int qg  = w >> 1;             // 0..1
    const int vq  = w & 1;              // 0..1 : v-half of 128
    const int q0  = qt * 64 + qg * 32;
    const int vb  = vq * 128;
    const int lane = threadIdx.x & 63;
    const int lq   = lane & 31;
    const int hi   = lane >> 5;

    const f16* qbase = theta2 + (size_t)b * 8 * L_ * 8;
    f16x8 Qf[4];
#pragma unroll
    for (int f = 0; f < 4; ++f)
        Qf[f] = *reinterpret_cast<const f16x8*>(
            qbase + ((size_t)(2 * f + hi) * L_ + q0 + lq) * 8);

    f32x16 acc[4] = {};
    float m_run = -3.0e38f;
    float l_run = 0.f;

    const f16* kbase = phi2 + (size_t)b * 8 * M_ * 8;
    const f16* vbase = g2 + (size_t)b * 256 * CV_ * 8;

    // 32-bit element offsets, incremented by constants per step.
    uint32_t ko[4], vo[2];
#pragma unroll
    for (int f = 0; f < 4; ++f) ko[f] = ((2 * f + hi) * M_ + mh * 1024 + lq) * 8u;
#pragma unroll
    for (int ch = 0; ch < 2; ++ch)
        vo[ch] = ((mh * 128 + 2 * ch + hi) * CV_ + vb + lq) * 8u;

    for (int it = 0; it < 32; ++it) {
        // ---- K loads (coalesced; shared by the vq pair via L1/L2) ----
        f16x8 Kf[4];
#pragma unroll
        for (int f = 0; f < 4; ++f)
            Kf[f] = *reinterpret_cast<const f16x8*>(kbase + ko[f]);

        // ---- QK^T (scores in log2 units): S^T[m][q], col = q ----
        f32x16 S = {};
        __builtin_amdgcn_s_setprio(1);
#pragma unroll
        for (int f = 0; f < 4; ++f) S = MFMA32(Kf[f], Qf[f], S);
        __builtin_amdgcn_s_setprio(0);

        // ---- online softmax, exp2 domain (per-lane; q is lane-local) ----
        float t0 = fmaxf(fmaxf(S[0], S[1]), S[2]);
        float t1 = fmaxf(fmaxf(S[3], S[4]), S[5]);
        float t2 = fmaxf(fmaxf(S[6], S[7]), S[8]);
        float t3 = fmaxf(fmaxf(S[9], S[10]), S[11]);
        float t4 = fmaxf(fmaxf(S[12], S[13]), S[14]);
        float tm = fmaxf(fmaxf(fmaxf(t0, t1), t2),
                         fmaxf(fmaxf(t3, t4), S[15]));
        tm = fmaxf(tm, __shfl_xor(tm, 32));
        if (__any(tm > m_run + 11.5f)) {  // wave-uniform defer-max
            const float m_new = fmaxf(m_run, tm);
            const float sc = __builtin_amdgcn_exp2f(m_run - m_new);
#pragma unroll
            for (int vt = 0; vt < 4; ++vt)
#pragma unroll
                for (int r = 0; r < 16; ++r) acc[vt][r] *= sc;
            l_run *= sc;
            m_run = m_new;
        }
        // exp2 in place into S (register economy)
#pragma unroll
        for (int r = 0; r < 16; ++r) S[r] = __builtin_amdgcn_exp2f(S[r] - m_run);
        float a0 = (S[0] + S[1]) + (S[2] + S[3]);
        float a1 = (S[4] + S[5]) + (S[6] + S[7]);
        float a2 = (S[8] + S[9]) + (S[10] + S[11]);
        float a3 = (S[12] + S[13]) + (S[14] + S[15]);
        l_run += (a0 + a1) + (a2 + a3);  // per-lane-half; merged in epilogue

        // ---- P -> f16 B-fragments (cvt_pkrtz + permlane32_swap, T12) ----
        uint32_t pk[8];
#pragma unroll
        for (int i = 0; i < 8; ++i) pk[i] = pkrtz(S[2 * i], S[2 * i + 1]);
        asm volatile("v_permlane32_swap_b32 %0, %1" : "+v"(pk[0]), "+v"(pk[2]));
        asm volatile("v_permlane32_swap_b32 %0, %1" : "+v"(pk[1]), "+v"(pk[3]));
        asm volatile("v_permlane32_swap_b32 %0, %1" : "+v"(pk[4]), "+v"(pk[6]));
        asm volatile("v_permlane32_swap_b32 %0, %1" : "+v"(pk[5]), "+v"(pk[7]));
        u32x4 fr0 = {pk[0], pk[1], pk[2], pk[3]};
        u32x4 fr1 = {pk[4], pk[5], pk[6], pk[7]};
        f16x8 P0 = __builtin_bit_cast(f16x8, fr0);
        f16x8 P1 = __builtin_bit_cast(f16x8, fr1);

        // ---- PV: ch0 (m 0-15) then ch1 (m 16-31), V staged 16 regs each ----
        {
            f16x8 Vf0[4];
#pragma unroll
            for (int vt = 0; vt < 4; ++vt)
                Vf0[vt] = *reinterpret_cast<const f16x8*>(vbase + vo[0] + vt * 32 * 8);
            __builtin_amdgcn_s_setprio(1);
#pragma unroll
            for (int vt = 0; vt < 4; ++vt) acc[vt] = MFMA32(Vf0[vt], P0, acc[vt]);
            __builtin_amdgcn_s_setprio(0);
        }
        {
            f16x8 Vf1[4];
#pragma unroll
            for (int vt = 0; vt < 4; ++vt)
                Vf1[vt] = *reinterpret_cast<const f16x8*>(vbase + vo[1] + vt * 32 * 8);
            __builtin_amdgcn_s_setprio(1);
#pragma unroll
            for (int vt = 0; vt < 4; ++vt) acc[vt] = MFMA32(Vf1[vt], P1, acc[vt]);
            __builtin_amdgcn_s_setprio(0);
        }

        // ---- advance offsets (uniform constants) ----
#pragma unroll
        for (int f = 0; f < 4; ++f) ko[f] += 32u * 8u;   // +32 m
        vo[0] += 4u * CV_ * 8u;                          // +4 m-octets
        vo[1] += 4u * CV_ * 8u;
    }

    // ---- epilogue: normalize partial, store op[mh] + (m, l) ----
    const float l_full = l_run + __shfl_xor(l_run, 32);
    const float inv = 1.f / l_full;
    const int qtile = (q0 >> 4) + (lq >> 4);
    const int ql    = lq & 15;
    f16* opm = op + (size_t)mh * B_ * L_ * CV_;
#pragma unroll
    for (int vt = 0; vt < 4; ++vt)
#pragma unroll
        for (int rq = 0; rq < 4; ++rq) {
            f16x4 o;
#pragma unroll
            for (int j = 0; j < 4; ++j) o[j] = (f16)(acc[vt][4 * rq + j] * inv);
            f16* p = opm + ((((size_t)b * 256 + qtile) * 8 + vq * 4 + vt) * 64 +
                            rq * 16 + ql) * 8 + 4 * hi;
            *reinterpret_cast<f16x4*>(p) = o;
        }
    if (vq == 0 && hi == 0) {  // one half-warp per qg writes per-q stats
        const int q = q0 + lq;
        mlm[(size_t)mh * B_ * L_ + (size_t)b * L_ + q] = m_run;
        mll[(size_t)mh * B_ * L_ + (size_t)b * L_ + q] = l_full;
    }
}

// ---------------------------------------------------------------------------
// Kernel C: MFMA output projection + residual, 64l x 256oc blocks (4
//   oc-tiles per warp). Per ks: 4 A-loads + 4 ds_reads feed 16 MFMAs
//   (r20 ratio was 2+4:8) — halves o2 L2 re-reads (128 -> 64 MB) and WoF
//   re-reads, and halves block count. acc[4][4] = 64 AGPR + ~40 VGPR live
//   at plain launch_bounds(256): ~4 waves/SIMD (LDS 32.5 KB -> 4 blk/CU).
//   Flash-combine per block into LDS (r20-verified stages 1-2 unchanged).
// ---------------------------------------------------------------------------
__global__ __launch_bounds__(256) void out_mfma(const f16* __restrict__ WoF,
                                                const f16* __restrict__ op,
                                                const float* __restrict__ mlm,
                                                const float* __restrict__ mll,
                                                const float* __restrict__ x,
                                                const float* __restrict__ gamma_p,
                                                float* __restrict__ out) {
    __shared__ __align__(16) f16 os[4 * 8 * 64 * 8];  // 32 KB: [lt][ks][lane][8]
    __shared__ float aAs[64], aBs[64];
    const int b    = blockIdx.z;
    const int l0   = blockIdx.x * 64;
    const int tid  = threadIdx.x;
    const int wid  = tid >> 6;
    const int oc0  = blockIdx.y * 256 + wid * 64;  // four 16-oc tiles per warp
    const int lane = tid & 63;
    const int lq   = lane & 15;
    const int g    = lane >> 4;
    const size_t PSZ = (size_t)B_ * L_ * CV_;

    // ---- stage 1: per-q blend weights (q = l0 + tid, tid < 64) ----
    if (tid < 64) {
        const size_t mi = (size_t)b * L_ + l0 + tid;
        const float mA = mlm[mi],            lA = mll[mi];
        const float mB = mlm[B_ * L_ + mi],  lB = mll[B_ * L_ + mi];
        const float ms = fmaxf(mA, mB);
        const float wA = __builtin_amdgcn_exp2f(mA - ms) * lA;
        const float wB = __builtin_amdgcn_exp2f(mB - ms) * lB;
        const float d  = wA + wB;
        aAs[tid] = wA / d;
        aBs[tid] = wB / d;
    }
    __syncthreads();

    // ---- stage 2: blend both partials' slice into LDS ----
    // chunk ch = lt*512 + ks*64 + lane' (2048 chunks of 8 f16); in-chunk
    // element (q,v): q = l0 + lt*16 + (lane'&15).
    {
        const size_t gbase = (size_t)(b * 256 + (l0 >> 4)) * 4096;
#pragma unroll
        for (int i = 0; i < 8; ++i) {
            const int ch = i * 256 + tid;
            const size_t fo = gbase + (size_t)ch * 8;
            const f16x8 va = *reinterpret_cast<const f16x8*>(op + fo);
            const f16x8 vb = *reinterpret_cast<const f16x8*>(op + PSZ + fo);
            const int qi = ((ch >> 9) << 4) + (ch & 15);  // lt*16 + (lane'&15)
            const float aA = aAs[qi], aB = aBs[qi];
            u32x4 pb;
#pragma unroll
            for (int jp = 0; jp < 4; ++jp)
                pb[jp] = pkrtz((float)va[2 * jp] * aA + (float)vb[2 * jp] * aB,
                               (float)va[2 * jp + 1] * aA + (float)vb[2 * jp + 1] * aB);
            *reinterpret_cast<u32x4*>(&os[ch * 8]) = pb;
        }
    }
    __syncthreads();

    // ---- stage 3: GEMM from LDS, 4 oc-tiles per warp ----
    f32x4 acc[4][4] = {};
#pragma unroll
    for (int ks = 0; ks < 8; ++ks) {
        f16x8 A[4];
#pragma unroll
        for (int ot = 0; ot < 4; ++ot)
            A[ot] = *reinterpret_cast<const f16x8*>(
                WoF + (((size_t)((oc0 >> 4) + ot) * 8 + ks) * 64 + lane) * 8);
#pragma unroll
        for (int lt = 0; lt < 4; ++lt) {
            const f16x8 Bf = *reinterpret_cast<const f16x8*>(
                &os[((lt * 8 + ks) * 64 + lane) * 8]);
#pragma unroll
            for (int ot = 0; ot < 4; ++ot)
                acc[ot][lt] = MFMA16(A[ot], Bf, acc[ot][lt]);
        }
    }
    const float gamma = *gamma_p;
#pragma unroll
    for (int ot = 0; ot < 4; ++ot)
#pragma unroll
        for (int lt = 0; lt < 4; ++lt)
#pragma unroll
            for (int r = 0; r < 4; ++r) {
                const size_t o = ((size_t)b * C_ + oc0 + ot * 16 + 4 * g + r) * L_ +
                                 l0 + lt * 16 + lq;
                out[o] = fmaf(gamma, acc[ot][lt][r], x[o]);
            }
}

// ---------------------------------------------------------------------------
extern "C" void kernel_launch(void* const* d_in, const int* in_sizes, int n_in,
                              void* d_out, int out_size, void* d_ws, size_t ws_size,
                              hipStream_t stream) {
    const float* x       = (const float*)d_in[0];
    const float* W_theta = (const float*)d_in[1];
    const float* W_phi   = (const float*)d_in[2];
    const float* W_g     = (const float*)d_in[3];
    const float* W_o     = (const float*)d_in[4];
    const float* gamma   = (const float*)d_in[5];
    float* out = (float*)d_out;

    // workspace carve: theta2 | phi2 | g2 | WoF | WallF | mlm | mll | op[2]
    f16* theta2 = (f16*)d_ws;                          // 4 MiB
    f16* phi2   = theta2 + (size_t)B_ * 8 * L_ * 8;    // 2 MiB
    f16* g2     = phi2 + (size_t)B_ * 8 * M_ * 8;      // 8 MiB
    f16* WoF    = g2 + (size_t)B_ * 256 * CV_ * 8;     // 0.25 MiB
    f16* WallF  = WoF + (size_t)C_ * CV_;              // 0.375 MiB
    float* mlm  = (float*)(WallF + (size_t)384 * C_);  // [2][B][L] 0.25 MiB
    float* mll  = mlm + (size_t)2 * B_ * L_;           // [2][B][L] 0.25 MiB
    f16* op     = (f16*)(mll + (size_t)2 * B_ * L_);   // [2][B][L][CV] 32 MiB

    const int cvt_n = 384 * 512 + 512 * 256;  // 327680
    cvt_all<<<dim3(cvt_n / 256), 256, 0, stream>>>(W_theta, W_phi, W_g, W_o, WallF, WoF);
    fused_proj<<<dim3(L_ / 32, B_), 256, 0, stream>>>(WallF, x, theta2, phi2, g2);
    attn_flash<<<dim3(512, 2), 256, 0, stream>>>(theta2, phi2, g2, op, mlm, mll);
    out_mfma<<<dim3(L_ / 64, C_ / 256, B_), 256, 0, stream>>>(WoF, op, mlm, mll,
                                                              x, gamma, out);
}

// Round 22
// 151.073 us; speedup vs baseline: 1.0221x; 1.0221x over previous
//
#include <hip/hip_runtime.h>
#include <cstdint>
#include <cstddef>

// Problem constants
#define B_ 8
#define C_ 512
#define L_ 4096
#define M_ 2048   // L/2 (pooled keys)
#define CK_ 64    // C/8
#define CV_ 256   // C/2

typedef _Float16 f16;
typedef _Float16 f16x8 __attribute__((ext_vector_type(8)));
typedef _Float16 f16x4 __attribute__((ext_vector_type(4)));
typedef float f32x4 __attribute__((ext_vector_type(4)));
typedef float f32x16 __attribute__((ext_vector_type(16)));
typedef unsigned int u32x4 __attribute__((ext_vector_type(4)));

#define MFMA16(A, Bv, Cv) __builtin_amdgcn_mfma_f32_16x16x32_f16(A, Bv, Cv, 0, 0, 0)
#define MFMA32(A, Bv, Cv) __builtin_amdgcn_mfma_f32_32x32x16_f16(A, Bv, Cv, 0, 0, 0)

#define LOG2E 1.44269504f

static __device__ __forceinline__ uint32_t pkrtz(float a, float b) {
    return __builtin_bit_cast(uint32_t, __builtin_amdgcn_cvt_pkrtz(a, b));
}

// ---------------------------------------------------------------------------
// Kernel W: weight conversion into FRAGMENT-NATIVE layouts. (r11-verified)
// ---------------------------------------------------------------------------
__global__ __launch_bounds__(256) void cvt_all(const float* __restrict__ Wt,
                                               const float* __restrict__ Wp,
                                               const float* __restrict__ Wg,
                                               const float* __restrict__ Wo,
                                               f16* __restrict__ WallF,
                                               f16* __restrict__ WoF) {
    const int i = blockIdx.x * 256 + threadIdx.x;
    const int NW = 384 * 512;  // 196608
    if (i < NW) {
        const int och = i >> 9, c = i & 511;
        float v;
        if (och < 64)       v = Wt[i];
        else if (och < 128) v = Wp[i - 64 * 512];
        else                v = Wg[i - 128 * 512];
        const int idx = (((och >> 4) * 16 + (c >> 5)) * 64 +
                         (((c >> 3) & 3) << 4) + (och & 15)) * 8 + (c & 7);
        WallF[idx] = (f16)v;
    } else {
        const int j = i - NW;  // < 131072
        const int oc = j >> 8, v = j & 255;
        const int idx = (((oc >> 4) * 8 + (v >> 5)) * 64 +
                         (((v >> 3) & 3) << 4) + (oc & 15)) * 8 + (v & 7);
        WoF[idx] = (f16)Wo[j];
    }
}

// ---------------------------------------------------------------------------
// Fused projection kernel (MFMA f16, fp32 accum), x staged via LDS.
//   (r11-verified, unchanged)
// ---------------------------------------------------------------------------
__global__ __launch_bounds__(256) void fused_proj(const f16* __restrict__ WallF,
                                                  const float* __restrict__ x,
                                                  f16* __restrict__ theta2,
                                                  f16* __restrict__ phi2,
                                                  f16* __restrict__ g2) {
    __shared__ __align__(16) f16 xs[64][32][8];  // 32 KB
    const int b    = blockIdx.y;
    const int l0   = blockIdx.x * 32;
    const int tid  = threadIdx.x;
    const int w    = tid >> 6;           // warp: och range [w*96, w*96+96)
    const int lane = tid & 63;
    const int lq   = lane & 15;
    const int g    = lane >> 4;
    const int wb   = w * 96;

    // ---- stage x tile -> LDS (f16, fragment-native) ----
    {
        const float* xb = x + (size_t)b * C_ * L_ + l0 + (tid & 31);
        const int co0 = tid >> 5;  // 0..7
#pragma unroll
        for (int i = 0; i < 8; ++i) {
            const int co = i * 8 + co0;
            float v[8];
#pragma unroll
            for (int j = 0; j < 8; ++j) v[j] = xb[(size_t)(co * 8 + j) * L_];
            u32x4 p = {pkrtz(v[0], v[1]), pkrtz(v[2], v[3]),
                       pkrtz(v[4], v[5]), pkrtz(v[6], v[7])};
            *reinterpret_cast<u32x4*>(&xs[co][tid & 31][0]) = p;
        }
    }
    __syncthreads();

    f32x4 acc[6][2] = {};
    for (int ks = 0; ks < 16; ++ks) {
        f16x8 Bf[2];
#pragma unroll
        for (int lt = 0; lt < 2; ++lt)
            Bf[lt] = *reinterpret_cast<const f16x8*>(&xs[ks * 4 + g][lt * 16 + lq][0]);
#pragma unroll
        for (int t = 0; t < 6; ++t) {
            f16x8 Af = *reinterpret_cast<const f16x8*>(
                WallF + (((size_t)(6 * w + t) * 16 + ks) * 64 + lane) * 8);
            acc[t][0] = MFMA16(Af, Bf[0], acc[t][0]);
            acc[t][1] = MFMA16(Af, Bf[1], acc[t][1]);
        }
    }

    // Epilogue. D layout (MFMA16): row = 4g + r (och), col = lq (l).
#pragma unroll
    for (int t = 0; t < 6; ++t) {
        const int och0 = wb + t * 16;
#pragma unroll
        for (int lt = 0; lt < 2; ++lt) {
            const int l = l0 + lt * 16 + lq;
            if (och0 < 64) {
#pragma unroll
                for (int r = 0; r < 4; ++r) {
                    const int och = och0 + 4 * g + r;
                    theta2[(((size_t)b * 8 + (och >> 3)) * L_ + l) * 8 + (och & 7)] =
                        (f16)(acc[t][lt][r] * LOG2E);
                }
            } else {
#pragma unroll
                for (int r = 0; r < 4; ++r) {
                    const float pv = fmaxf(acc[t][lt][r], __shfl_xor(acc[t][lt][r], 1));
                    if (!(lane & 1)) {
                        const int m = l >> 1;
                        if (och0 < 128) {
                            const int kc = och0 - 64 + 4 * g + r;
                            phi2[(((size_t)b * 8 + (kc >> 3)) * M_ + m) * 8 + (kc & 7)] =
                                (f16)pv;
                        } else {
                            const int vc = och0 - 128 + 4 * g + r;
                            g2[(((size_t)b * 256 + (m >> 3)) * CV_ + vc) * 8 + (m & 7)] =
                                (f16)pv;
                        }
                    }
                }
            }
        }
    }
}

// ---------------------------------------------------------------------------
// Kernel B: flash attention, split-M across blocks (grid.y = mh), vq = 2.
//   EXACT r15-verified body (best measured: 79.3 µs; register-equilibrium
//   accepted per r16 — NMH=4 and occupancy probes were null).
// ---------------------------------------------------------------------------
__global__ __launch_bounds__(256, 3) void attn_flash(const f16* __restrict__ theta2,
                                                     const f16* __restrict__ phi2,
                                                     const f16* __restrict__ g2,
                                                     f16* __restrict__ op,
                                                     float* __restrict__ mlm,
                                                     float* __restrict__ mll) {
    const int bid = blockIdx.x;
    const int mh  = blockIdx.y;         // m-stripe of 1024
    const int b   = bid & 7;            // XCD-major: one batch per XCD
    const int qt  = bid >> 3;           // 64 q-tiles (of 64) per batch
    const int w   = threadIdx.x >> 6;   // 0..3
    const int qg  = w >> 1;             // 0..1
    const int vq  = w & 1;              // 0..1 : v-half of 128
    const int q0  = qt * 64 + qg * 32;
    const int vb  = vq * 128;
    const int lane = threadIdx.x & 63;
    const int lq   = lane & 31;
    const int hi   = lane >> 5;

    const f16* qbase = theta2 + (size_t)b * 8 * L_ * 8;
    f16x8 Qf[4];
#pragma unroll
    for (int f = 0; f < 4; ++f)
        Qf[f] = *reinterpret_cast<const f16x8*>(
            qbase + ((size_t)(2 * f + hi) * L_ + q0 + lq) * 8);

    f32x16 acc[4] = {};
    float m_run = -3.0e38f;
    float l_run = 0.f;

    const f16* kbase = phi2 + (size_t)b * 8 * M_ * 8;
    const f16* vbase = g2 + (size_t)b * 256 * CV_ * 8;

    // 32-bit element offsets, incremented by constants per step.
    uint32_t ko[4], vo[2];
#pragma unroll
    for (int f = 0; f < 4; ++f) ko[f] = ((2 * f + hi) * M_ + mh * 1024 + lq) * 8u;
#pragma unroll
    for (int ch = 0; ch < 2; ++ch)
        vo[ch] = ((mh * 128 + 2 * ch + hi) * CV_ + vb + lq) * 8u;

    for (int it = 0; it < 32; ++it) {
        // ---- K loads (coalesced; shared by the vq pair via L1/L2) ----
        f16x8 Kf[4];
#pragma unroll
        for (int f = 0; f < 4; ++f)
            Kf[f] = *reinterpret_cast<const f16x8*>(kbase + ko[f]);

        // ---- QK^T (scores in log2 units): S^T[m][q], col = q ----
        f32x16 S = {};
        __builtin_amdgcn_s_setprio(1);
#pragma unroll
        for (int f = 0; f < 4; ++f) S = MFMA32(Kf[f], Qf[f], S);
        __builtin_amdgcn_s_setprio(0);

        // ---- online softmax, exp2 domain (per-lane; q is lane-local) ----
        float t0 = fmaxf(fmaxf(S[0], S[1]), S[2]);
        float t1 = fmaxf(fmaxf(S[3], S[4]), S[5]);
        float t2 = fmaxf(fmaxf(S[6], S[7]), S[8]);
        float t3 = fmaxf(fmaxf(S[9], S[10]), S[11]);
        float t4 = fmaxf(fmaxf(S[12], S[13]), S[14]);
        float tm = fmaxf(fmaxf(fmaxf(t0, t1), t2),
                         fmaxf(fmaxf(t3, t4), S[15]));
        tm = fmaxf(tm, __shfl_xor(tm, 32));
        if (__any(tm > m_run + 11.5f)) {  // wave-uniform defer-max
            const float m_new = fmaxf(m_run, tm);
            const float sc = __builtin_amdgcn_exp2f(m_run - m_new);
#pragma unroll
            for (int vt = 0; vt < 4; ++vt)
#pragma unroll
                for (int r = 0; r < 16; ++r) acc[vt][r] *= sc;
            l_run *= sc;
            m_run = m_new;
        }
        // exp2 in place into S (register economy)
#pragma unroll
        for (int r = 0; r < 16; ++r) S[r] = __builtin_amdgcn_exp2f(S[r] - m_run);
        float a0 = (S[0] + S[1]) + (S[2] + S[3]);
        float a1 = (S[4] + S[5]) + (S[6] + S[7]);
        float a2 = (S[8] + S[9]) + (S[10] + S[11]);
        float a3 = (S[12] + S[13]) + (S[14] + S[15]);
        l_run += (a0 + a1) + (a2 + a3);  // per-lane-half; merged in epilogue

        // ---- P -> f16 B-fragments (cvt_pkrtz + permlane32_swap, T12) ----
        uint32_t pk[8];
#pragma unroll
        for (int i = 0; i < 8; ++i) pk[i] = pkrtz(S[2 * i], S[2 * i + 1]);
        asm volatile("v_permlane32_swap_b32 %0, %1" : "+v"(pk[0]), "+v"(pk[2]));
        asm volatile("v_permlane32_swap_b32 %0, %1" : "+v"(pk[1]), "+v"(pk[3]));
        asm volatile("v_permlane32_swap_b32 %0, %1" : "+v"(pk[4]), "+v"(pk[6]));
        asm volatile("v_permlane32_swap_b32 %0, %1" : "+v"(pk[5]), "+v"(pk[7]));
        u32x4 fr0 = {pk[0], pk[1], pk[2], pk[3]};
        u32x4 fr1 = {pk[4], pk[5], pk[6], pk[7]};
        f16x8 P0 = __builtin_bit_cast(f16x8, fr0);
        f16x8 P1 = __builtin_bit_cast(f16x8, fr1);

        // ---- PV: ch0 (m 0-15) then ch1 (m 16-31), V staged 16 regs each ----
        {
            f16x8 Vf0[4];
#pragma unroll
            for (int vt = 0; vt < 4; ++vt)
                Vf0[vt] = *reinterpret_cast<const f16x8*>(vbase + vo[0] + vt * 32 * 8);
            __builtin_amdgcn_s_setprio(1);
#pragma unroll
            for (int vt = 0; vt < 4; ++vt) acc[vt] = MFMA32(Vf0[vt], P0, acc[vt]);
            __builtin_amdgcn_s_setprio(0);
        }
        {
            f16x8 Vf1[4];
#pragma unroll
            for (int vt = 0; vt < 4; ++vt)
                Vf1[vt] = *reinterpret_cast<const f16x8*>(vbase + vo[1] + vt * 32 * 8);
            __builtin_amdgcn_s_setprio(1);
#pragma unroll
            for (int vt = 0; vt < 4; ++vt) acc[vt] = MFMA32(Vf1[vt], P1, acc[vt]);
            __builtin_amdgcn_s_setprio(0);
        }

        // ---- advance offsets (uniform constants) ----
#pragma unroll
        for (int f = 0; f < 4; ++f) ko[f] += 32u * 8u;   // +32 m
        vo[0] += 4u * CV_ * 8u;                          // +4 m-octets
        vo[1] += 4u * CV_ * 8u;
    }

    // ---- epilogue: normalize partial, store op[mh] + (m, l) ----
    const float l_full = l_run + __shfl_xor(l_run, 32);
    const float inv = 1.f / l_full;
    const int qtile = (q0 >> 4) + (lq >> 4);
    const int ql    = lq & 15;
    f16* opm = op + (size_t)mh * B_ * L_ * CV_;
#pragma unroll
    for (int vt = 0; vt < 4; ++vt)
#pragma unroll
        for (int rq = 0; rq < 4; ++rq) {
            f16x4 o;
#pragma unroll
            for (int j = 0; j < 4; ++j) o[j] = (f16)(acc[vt][4 * rq + j] * inv);
            f16* p = opm + ((((size_t)b * 256 + qtile) * 8 + vq * 4 + vt) * 64 +
                            rq * 16 + ql) * 8 + 4 * hi;
            *reinterpret_cast<f16x4*>(p) = o;
        }
    if (vq == 0 && hi == 0) {  // one half-warp per qg writes per-q stats
        const int q = q0 + lq;
        mlm[(size_t)mh * B_ * L_ + (size_t)b * L_ + q] = m_run;
        mll[(size_t)mh * B_ * L_ + (size_t)b * L_ + q] = l_full;
    }
}

// ---------------------------------------------------------------------------
// Kernel C: MFMA output projection + residual, 64l x 128oc blocks, with the
//   flash-combine done ONCE PER BLOCK into LDS. (r20-verified, byte-exact —
//   r21's 256-oc widening regressed ~2 µs and is reverted.)
// ---------------------------------------------------------------------------
__global__ __launch_bounds__(256) void out_mfma(const f16* __restrict__ WoF,
                                                const f16* __restrict__ op,
                                                const float* __restrict__ mlm,
                                                const float* __restrict__ mll,
                                                const float* __restrict__ x,
                                                const float* __restrict__ gamma_p,
                                                float* __restrict__ out) {
    __shared__ __align__(16) f16 os[4 * 8 * 64 * 8];  // 32 KB: [lt][ks][lane][8]
    __shared__ float aAs[64], aBs[64];
    const int b    = blockIdx.z;
    const int l0   = blockIdx.x * 64;
    const int tid  = threadIdx.x;
    const int wid  = tid >> 6;
    const int oc0  = blockIdx.y * 128 + wid * 32;  // two 16-oc tiles per warp
    const int lane = tid & 63;
    const int lq   = lane & 15;
    const int g    = lane >> 4;
    const size_t PSZ = (size_t)B_ * L_ * CV_;

    // ---- stage 1: per-q blend weights (q = l0 + tid, tid < 64) ----
    if (tid < 64) {
        const size_t mi = (size_t)b * L_ + l0 + tid;
        const float mA = mlm[mi],            lA = mll[mi];
        const float mB = mlm[B_ * L_ + mi],  lB = mll[B_ * L_ + mi];
        const float ms = fmaxf(mA, mB);
        const float wA = __builtin_amdgcn_exp2f(mA - ms) * lA;
        const float wB = __builtin_amdgcn_exp2f(mB - ms) * lB;
        const float d  = wA + wB;
        aAs[tid] = wA / d;
        aBs[tid] = wB / d;
    }
    __syncthreads();

    // ---- stage 2: blend both partials' slice into LDS ----
    // chunk ch = lt*512 + ks*64 + lane' (2048 chunks of 8 f16); in-chunk
    // element (q,v): q = l0 + lt*16 + (lane'&15).
    {
        const size_t gbase = (size_t)(b * 256 + (l0 >> 4)) * 4096;
#pragma unroll
        for (int i = 0; i < 8; ++i) {
            const int ch = i * 256 + tid;
            const size_t fo = gbase + (size_t)ch * 8;
            const f16x8 va = *reinterpret_cast<const f16x8*>(op + fo);
            const f16x8 vb = *reinterpret_cast<const f16x8*>(op + PSZ + fo);
            const int qi = ((ch >> 9) << 4) + (ch & 15);  // lt*16 + (lane'&15)
            const float aA = aAs[qi], aB = aBs[qi];
            u32x4 pb;
#pragma unroll
            for (int jp = 0; jp < 4; ++jp)
                pb[jp] = pkrtz((float)va[2 * jp] * aA + (float)vb[2 * jp] * aB,
                               (float)va[2 * jp + 1] * aA + (float)vb[2 * jp + 1] * aB);
            *reinterpret_cast<u32x4*>(&os[ch * 8]) = pb;
        }
    }
    __syncthreads();

    // ---- stage 3: GEMM from LDS ----
    f32x4 acc[2][4] = {};
#pragma unroll
    for (int ks = 0; ks < 8; ++ks) {
        f16x8 A0 = *reinterpret_cast<const f16x8*>(
            WoF + (((size_t)(oc0 >> 4) * 8 + ks) * 64 + lane) * 8);
        f16x8 A1 = *reinterpret_cast<const f16x8*>(
            WoF + (((size_t)((oc0 >> 4) + 1) * 8 + ks) * 64 + lane) * 8);
#pragma unroll
        for (int lt = 0; lt < 4; ++lt) {
            const f16x8 Bf = *reinterpret_cast<const f16x8*>(
                &os[((lt * 8 + ks) * 64 + lane) * 8]);
            acc[0][lt] = MFMA16(A0, Bf, acc[0][lt]);
            acc[1][lt] = MFMA16(A1, Bf, acc[1][lt]);
        }
    }
    const float gamma = *gamma_p;
#pragma unroll
    for (int ot = 0; ot < 2; ++ot)
#pragma unroll
        for (int lt = 0; lt < 4; ++lt)
#pragma unroll
            for (int r = 0; r < 4; ++r) {
                const size_t o = ((size_t)b * C_ + oc0 + ot * 16 + 4 * g + r) * L_ +
                                 l0 + lt * 16 + lq;
                out[o] = fmaf(gamma, acc[ot][lt][r], x[o]);
            }
}

// ---------------------------------------------------------------------------
extern "C" void kernel_launch(void* const* d_in, const int* in_sizes, int n_in,
                              void* d_out, int out_size, void* d_ws, size_t ws_size,
                              hipStream_t stream) {
    const float* x       = (const float*)d_in[0];
    const float* W_theta = (const float*)d_in[1];
    const float* W_phi   = (const float*)d_in[2];
    const float* W_g     = (const float*)d_in[3];
    const float* W_o     = (const float*)d_in[4];
    const float* gamma   = (const float*)d_in[5];
    float* out = (float*)d_out;

    // workspace carve: theta2 | phi2 | g2 | WoF | WallF | mlm | mll | op[2]
    f16* theta2 = (f16*)d_ws;                          // 4 MiB
    f16* phi2   = theta2 + (size_t)B_ * 8 * L_ * 8;    // 2 MiB
    f16* g2     = phi2 + (size_t)B_ * 8 * M_ * 8;      // 8 MiB
    f16* WoF    = g2 + (size_t)B_ * 256 * CV_ * 8;     // 0.25 MiB
    f16* WallF  = WoF + (size_t)C_ * CV_;              // 0.375 MiB
    float* mlm  = (float*)(WallF + (size_t)384 * C_);  // [2][B][L] 0.25 MiB
    float* mll  = mlm + (size_t)2 * B_ * L_;           // [2][B][L] 0.25 MiB
    f16* op     = (f16*)(mll + (size_t)2 * B_ * L_);   // [2][B][L][CV] 32 MiB

    const int cvt_n = 384 * 512 + 512 * 256;  // 327680
    cvt_all<<<dim3(cvt_n / 256), 256, 0, stream>>>(W_theta, W_phi, W_g, W_o, WallF, WoF);
    fused_proj<<<dim3(L_ / 32, B_), 256, 0, stream>>>(WallF, x, theta2, phi2, g2);
    attn_flash<<<dim3(512, 2), 256, 0, stream>>>(theta2, phi2, g2, op, mlm, mll);
    out_mfma<<<dim3(L_ / 64, C_ / 128, B_), 256, 0, stream>>>(WoF, op, mlm, mll,
                                                              x, gamma, out);
}